// Round 10
// baseline (243.048 us; speedup 1.0000x reference)
//
#include <hip/hip_runtime.h>

#define G 4096
#define P1_BLOCKS 2048   // 512 stripes x 4 col-quarters (16-row stripes) — R8 exact
#define P3_BLOCKS 2048   // 2 adj rows per block (32 KB) — R8 exact
#define NTHR 256
#define SHARDS 64        // finalize accumulator shards (128 B apart -> low contention)

typedef float f4 __attribute__((ext_vector_type(4)));

// ws float offsets
#define OFF_PART 0          // part[512][4096] = 2097152 floats (8 MiB) — R8 exact
#define OFF_VMAG 2097152    // 4096 floats
#define OFF_ACC  2101248    // acc_t shard k at +k*32; acc_n shard k at +2048+k*32 (int);
                            // ticket at +4096. Zeroed by K1 block 0.

#define AGENT __HIP_MEMORY_SCOPE_AGENT
#define RLX   __ATOMIC_RELAXED

// ---------------------------------------------------------------------------
// K1 (P1): R8-exact body — |velocity| column sums over 512 stripes of 16 rows,
// NT loads (non-allocating: don't evict the harness's dirty poison lines ->
// no write-back storm; +15.8 µs proven in R8). Block 0 additionally zeroes
// the sharded finalize accumulators (R6/R9-proven cross-dispatch init).
// ---------------------------------------------------------------------------
__global__ __launch_bounds__(NTHR) void vmag_partial(const float* __restrict__ vel,
                                                     float* __restrict__ part,
                                                     float* __restrict__ acc) {
    if (blockIdx.x == 0) {
        if (threadIdx.x < SHARDS) {
            acc[threadIdx.x * 32] = 0.f;                      // acc_t shards
            ((int*)acc)[2048 + threadIdx.x * 32] = 0;         // acc_n shards
        }
        if (threadIdx.x == SHARDS) ((unsigned*)acc)[4096] = 0u;  // ticket
    }

    const int col0 = (blockIdx.x & 3) * 1024 + threadIdx.x * 4;
    const int stripe = blockIdx.x >> 2;   // 0..511
    const float* p = vel + (size_t)stripe * 16 * G + col0;
    float ax = 0.f, ay = 0.f, az = 0.f, aw = 0.f;
#pragma unroll
    for (int r = 0; r < 16; ++r) {
        f4 v = __builtin_nontemporal_load((const f4*)p);
        ax += fabsf(v.x); ay += fabsf(v.y); az += fabsf(v.z); aw += fabsf(v.w);
        p += G;
    }
    f4 o = {ax, ay, az, aw};
    *(f4*)(part + (size_t)stripe * G + col0) = o;  // cached: re-read by K2
}

// ---------------------------------------------------------------------------
// K2 (P2): R8-exact — 32 blocks; block b reduces cols [b*128,+128) over 512
// stripes. part (8 MB) flows through cache once.
// ---------------------------------------------------------------------------
__global__ __launch_bounds__(NTHR) void vmag_reduce(const float* __restrict__ part,
                                                    float* __restrict__ vmag) {
    __shared__ f4 red[NTHR];
    const int t = threadIdx.x;
    const int c4 = t & 31;
    const int s0 = t >> 5;
    const int col0 = blockIdx.x * 128 + c4 * 4;
    f4 acc = {0.f, 0.f, 0.f, 0.f};
#pragma unroll
    for (int k = 0; k < 64; ++k)
        acc += *(const f4*)(part + (size_t)(s0 + 8 * k) * G + col0);
    red[t] = acc;  // red[s0*32 + c4]
    __syncthreads();
#pragma unroll
    for (int off = 128; off >= 32; off >>= 1) {
        if (t < off) red[t] += red[t + off];
        __syncthreads();
    }
    if (t < 32) {
        f4 a = red[t] * (1.0f / 8192.0f);
        *(f4*)(vmag + blockIdx.x * 128 + t * 4) = a;
    }
}

// ---------------------------------------------------------------------------
// K3 (P3+P4): R8-exact pair body (NT adj loads) + SHARDED atomic-RMW finalize.
// Block bid adds its (T,N) into shard bid&63 (32-way contention per address,
// shards on distinct 128-B lines). vmcnt(0) drains the block's own RMWs at
// the coherence point, THEN the ticket-add; the winner's post-ticket parallel
// fetch_add(...,0) reads therefore see all 2048 contributions (R6-proven
// ordering). No fences, no waiting; losers exit.
// ---------------------------------------------------------------------------
__global__ __launch_bounds__(NTHR) void pair_fin(const float* __restrict__ adj,
                                                 const float* __restrict__ vmag,
                                                 float* __restrict__ acc,
                                                 float* __restrict__ out) {
    const int tid = threadIdx.x;
    const int bid = blockIdx.x;

    f4 vjq[4];
#pragma unroll
    for (int q = 0; q < 4; ++q) vjq[q] = *(const f4*)(vmag + q * 1024 + tid * 4);
    const float vi0 = vmag[bid * 2];
    const float vi1 = vmag[bid * 2 + 1];

    const float* ablk = adj + (size_t)bid * 8192;
    float t = 0.f, nf = 0.f;
#pragma unroll
    for (int r = 0; r < 2; ++r) {
        const float vi = r ? vi1 : vi0;
        const float* arow = ablk + r * 4096;
#pragma unroll
        for (int q = 0; q < 4; ++q) {
            const f4 a = __builtin_nontemporal_load((const f4*)(arow + q * 1024 + tid * 4));
            const f4 vj = vjq[q];
            float a2;
            a2 = a.x * a.x; t = fmaf(fabsf(fmaf(a.x, -vi, vj.x)), a2, t); nf += a2;
            a2 = a.y * a.y; t = fmaf(fabsf(fmaf(a.y, -vi, vj.y)), a2, t); nf += a2;
            a2 = a.z * a.z; t = fmaf(fabsf(fmaf(a.z, -vi, vj.z)), a2, t); nf += a2;
            a2 = a.w * a.w; t = fmaf(fabsf(fmaf(a.w, -vi, vj.w)), a2, t); nf += a2;
        }
    }
#pragma unroll
    for (int off = 32; off > 0; off >>= 1) {
        t  += __shfl_down(t, off);
        nf += __shfl_down(nf, off);
    }
    __shared__ float st[4], snf[4];
    const int wave = tid >> 6;
    if ((tid & 63) == 0) { st[wave] = t; snf[wave] = nf; }
    __syncthreads();

    __shared__ int islast;
    if (tid == 0) {
        const float T = st[0] + st[1] + st[2] + st[3];
        const int   N = (int)(snf[0] + snf[1] + snf[2] + snf[3]);  // exact: <= 8192
        const int shard = bid & (SHARDS - 1);
        float* acc_t = acc + shard * 32;
        int*   acc_n = ((int*)acc) + 2048 + shard * 32;
        unsigned* cnt = ((unsigned*)acc) + 4096;

        (void)__hip_atomic_fetch_add(acc_t, T, RLX, AGENT);
        (void)__hip_atomic_fetch_add(acc_n, N, RLX, AGENT);
        asm volatile("s_waitcnt vmcnt(0)" ::: "memory");  // own RMWs done at LLC
        const unsigned tk = __hip_atomic_fetch_add(cnt, 1u, RLX, AGENT);
        islast = (tk == P3_BLOCKS - 1);
    }
    __syncthreads();

    if (islast) {
        __shared__ float wt[SHARDS];
        __shared__ int   wn[SHARDS];
        if (tid < SHARDS)
            wt[tid] = __hip_atomic_fetch_add(acc + tid * 32, 0.0f, RLX, AGENT);
        else if (tid < 2 * SHARDS)
            wn[tid - SHARDS] =
                __hip_atomic_fetch_add(((int*)acc) + 2048 + (tid - SHARDS) * 32, 0, RLX, AGENT);
        __syncthreads();
        if (tid == 0) {
            float T = 0.f;
            int   N = 0;
#pragma unroll
            for (int k = 0; k < SHARDS; ++k) { T += wt[k]; N += wn[k]; }
            out[0] = (N > 0) ? (T / fmaxf((float)N, 1.f)) : 0.f;
        }
    }
}

extern "C" void kernel_launch(void* const* d_in, const int* in_sizes, int n_in,
                              void* d_out, int out_size, void* d_ws, size_t ws_size,
                              hipStream_t stream) {
    const float* vel = (const float*)d_in[0];
    // d_in[1] (perturbation_idx) unused by the reference.
    const float* adj = (const float*)d_in[2];
    float* wsf  = (float*)d_ws;
    float* part = wsf + OFF_PART;
    float* vmag = wsf + OFF_VMAG;
    float* acc  = wsf + OFF_ACC;
    float* out  = (float*)d_out;

    vmag_partial<<<P1_BLOCKS, NTHR, 0, stream>>>(vel, part, acc);
    vmag_reduce<<<32, NTHR, 0, stream>>>(part, vmag);
    pair_fin<<<P3_BLOCKS, NTHR, 0, stream>>>(adj, vmag, acc, out);
}

// Round 11
// 225.852 us; speedup vs baseline: 1.0761x; 1.0761x over previous
//
#include <hip/hip_runtime.h>

#define G 4096
#define P1_BLOCKS 2048   // 512 stripes x 4 col-quarters (16-row stripes)
#define P3_BLOCKS 2048   // 2 adj rows per block (32 KB)
#define NTHR 256

typedef float f4 __attribute__((ext_vector_type(4)));

// ws float offsets
#define OFF_PART 0          // part[512][4096] = 2097152 floats (8 MiB)
#define OFF_VMAG 2097152    // 4096 floats
#define OFF_PT   2101248    // 2048 floats
#define OFF_PN   2103296    // 2048 ints

// ---------------------------------------------------------------------------
// P1: |velocity| column sums over 512 stripes of 16 rows.
// NONTEMPORAL vel loads: non-allocating, so the 134 MB stream does not evict
// the harness's dirty poison LLC lines (no write-back storm). This was the
// single real win of the session (-15.8 µs, R7->R8).
// ---------------------------------------------------------------------------
__global__ __launch_bounds__(NTHR) void vmag_partial(const float* __restrict__ vel,
                                                     float* __restrict__ part) {
    const int col0 = (blockIdx.x & 3) * 1024 + threadIdx.x * 4;
    const int stripe = blockIdx.x >> 2;   // 0..511
    const float* p = vel + (size_t)stripe * 16 * G + col0;
    float ax = 0.f, ay = 0.f, az = 0.f, aw = 0.f;
#pragma unroll
    for (int r = 0; r < 16; ++r) {
        f4 v = __builtin_nontemporal_load((const f4*)p);
        ax += fabsf(v.x); ay += fabsf(v.y); az += fabsf(v.z); aw += fabsf(v.w);
        p += G;
    }
    f4 o = {ax, ay, az, aw};
    *(f4*)(part + (size_t)stripe * G + col0) = o;  // cached: re-read by P2
}

// ---------------------------------------------------------------------------
// P2: 32 blocks; block b reduces cols [b*128, b*128+128) over 512 stripes.
// part (8 MB) flows through cache once.
// ---------------------------------------------------------------------------
__global__ __launch_bounds__(NTHR) void vmag_reduce(const float* __restrict__ part,
                                                    float* __restrict__ vmag) {
    __shared__ f4 red[NTHR];
    const int t = threadIdx.x;
    const int c4 = t & 31;
    const int s0 = t >> 5;
    const int col0 = blockIdx.x * 128 + c4 * 4;
    f4 acc = {0.f, 0.f, 0.f, 0.f};
#pragma unroll
    for (int k = 0; k < 64; ++k)
        acc += *(const f4*)(part + (size_t)(s0 + 8 * k) * G + col0);
    red[t] = acc;  // red[s0*32 + c4]
    __syncthreads();
#pragma unroll
    for (int off = 128; off >= 32; off >>= 1) {
        if (t < off) red[t] += red[t + off];
        __syncthreads();
    }
    if (t < 32) {
        f4 a = red[t] * (1.0f / 8192.0f);
        *(f4*)(vmag + blockIdx.x * 128 + t * 4) = a;
    }
}

// ---------------------------------------------------------------------------
// P3: pairwise pass, 2048 blocks, 2 adj rows per block (32 KB contiguous).
// NONTEMPORAL adj loads (same rationale as P1). Branchless bit-exact math:
// contrib = |vj - a*vi| * a^2 ; n += a^2  (a in {-1,0,1}).
// Plain partial stores; finalize is a separate tiny dispatch (measured
// strictly cheaper than any end-of-kernel atomic protocol: R6/R9/R10).
// ---------------------------------------------------------------------------
__global__ __launch_bounds__(NTHR) void pair_kernel(const float* __restrict__ adj,
                                                    const float* __restrict__ vmag,
                                                    float* __restrict__ pt,
                                                    int* __restrict__ pn) {
    const int tid = threadIdx.x;
    const int bid = blockIdx.x;

    f4 vjq[4];
#pragma unroll
    for (int q = 0; q < 4; ++q) vjq[q] = *(const f4*)(vmag + q * 1024 + tid * 4);
    const float vi0 = vmag[bid * 2];
    const float vi1 = vmag[bid * 2 + 1];

    const float* ablk = adj + (size_t)bid * 8192;
    float t = 0.f, nf = 0.f;
#pragma unroll
    for (int r = 0; r < 2; ++r) {
        const float vi = r ? vi1 : vi0;
        const float* arow = ablk + r * 4096;
#pragma unroll
        for (int q = 0; q < 4; ++q) {
            const f4 a = __builtin_nontemporal_load((const f4*)(arow + q * 1024 + tid * 4));
            const f4 vj = vjq[q];
            float a2;
            a2 = a.x * a.x; t = fmaf(fabsf(fmaf(a.x, -vi, vj.x)), a2, t); nf += a2;
            a2 = a.y * a.y; t = fmaf(fabsf(fmaf(a.y, -vi, vj.y)), a2, t); nf += a2;
            a2 = a.z * a.z; t = fmaf(fabsf(fmaf(a.z, -vi, vj.z)), a2, t); nf += a2;
            a2 = a.w * a.w; t = fmaf(fabsf(fmaf(a.w, -vi, vj.w)), a2, t); nf += a2;
        }
    }
#pragma unroll
    for (int off = 32; off > 0; off >>= 1) {
        t  += __shfl_down(t, off);
        nf += __shfl_down(nf, off);
    }
    __shared__ float st[4], snf[4];
    const int wave = tid >> 6;
    if ((tid & 63) == 0) { st[wave] = t; snf[wave] = nf; }
    __syncthreads();
    if (tid == 0) {
        pt[bid] = st[0] + st[1] + st[2] + st[3];
        pn[bid] = (int)(snf[0] + snf[1] + snf[2] + snf[3]);  // exact: <= 8192
    }
}

// ---------------------------------------------------------------------------
// P4: one 256-thread block reduces the 2048 partials.
// ---------------------------------------------------------------------------
__global__ __launch_bounds__(NTHR) void finalize(const float* __restrict__ pt,
                                                 const int* __restrict__ pn,
                                                 float* __restrict__ out) {
    const int tid = threadIdx.x;
    float t = 0.f;
    int n = 0;
#pragma unroll
    for (int k = 0; k < 8; ++k) {
        t += pt[tid + k * 256];
        n += pn[tid + k * 256];
    }
#pragma unroll
    for (int off = 32; off > 0; off >>= 1) {
        t += __shfl_down(t, off);
        n += __shfl_down(n, off);
    }
    __shared__ float st[4];
    __shared__ int sn[4];
    const int wave = tid >> 6;
    if ((tid & 63) == 0) { st[wave] = t; sn[wave] = n; }
    __syncthreads();
    if (tid == 0) {
        float tt = st[0] + st[1] + st[2] + st[3];
        int nn = sn[0] + sn[1] + sn[2] + sn[3];
        out[0] = (nn > 0) ? (tt / fmaxf((float)nn, 1.f)) : 0.f;
    }
}

extern "C" void kernel_launch(void* const* d_in, const int* in_sizes, int n_in,
                              void* d_out, int out_size, void* d_ws, size_t ws_size,
                              hipStream_t stream) {
    const float* vel = (const float*)d_in[0];
    // d_in[1] (perturbation_idx) unused by the reference.
    const float* adj = (const float*)d_in[2];
    float* wsf  = (float*)d_ws;
    float* part = wsf + OFF_PART;
    float* vmag = wsf + OFF_VMAG;
    float* pt   = wsf + OFF_PT;
    int*   pn   = (int*)(wsf + OFF_PN);
    float* out  = (float*)d_out;

    vmag_partial<<<P1_BLOCKS, NTHR, 0, stream>>>(vel, part);
    vmag_reduce<<<32, NTHR, 0, stream>>>(part, vmag);
    pair_kernel<<<P3_BLOCKS, NTHR, 0, stream>>>(adj, vmag, pt, pn);
    finalize<<<1, NTHR, 0, stream>>>(pt, pn, out);
}